// Round 8
// baseline (671.329 us; speedup 1.0000x reference)
//
#include <hip/hip_runtime.h>
#include <hip/hip_fp16.h>

constexpr int C = 128;
constexpr int N = 4096;
constexpr int B = 4;

typedef _Float16 f16x8 __attribute__((ext_vector_type(8)));
typedef _Float16 f16x4 __attribute__((ext_vector_type(4)));
typedef float    f32x4 __attribute__((ext_vector_type(4)));

// ---------------------------------------------------------------------------
// R8: one-shot weight convert fp32 -> f16 into workspace, concatenated:
// [w1(16K) | w2(16K) | wv(64K) | wt(64K) | wqk(16K)] elements.
// grid 176, 256 thr; each thread converts one float4.
// ---------------------------------------------------------------------------
__global__ __launch_bounds__(256) void k_wcvt(const float* __restrict__ w1,
                                              const float* __restrict__ w2,
                                              const float* __restrict__ wv,
                                              const float* __restrict__ wt,
                                              const float* __restrict__ wqk,
                                              _Float16* __restrict__ WF) {
  const int g = blockIdx.x * 256 + threadIdx.x;   // float4 index
  const float* src; int off;
  if (g < 4096)       { src = w1;  off = g; }
  else if (g < 8192)  { src = w2;  off = g - 4096; }
  else if (g < 24576) { src = wv;  off = g - 8192; }
  else if (g < 40960) { src = wt;  off = g - 24576; }
  else                { src = wqk; off = g - 40960; }
  const float4 v = ((const float4*)src)[off];
  f16x4 h = {(_Float16)v.x, (_Float16)v.y, (_Float16)v.z, (_Float16)v.w};
  *(f16x4*)&WF[(size_t)g * 4] = h;
}

// ---------------------------------------------------------------------------
// R8: MFMA projection GEMM. Y[b,o,n] = sum_c W[o,c]*X[b,c,n] (+bias), fp32 out.
// W is pre-converted f16 [o][c] (k-contiguous A operand, direct global loads).
// X staged as f16 transposed XT[n][c] in LDS (B^T operand).
// grid (N/64, 2, B), block 512 (8 waves: n-tile w&3, o-tiles {w>>2, w>>2+2}).
// STAT: contention-free BN partials bnpart[o*512 + part(+256)], part=bx*4+b.
// ---------------------------------------------------------------------------
template<bool BIAS, bool STAT>
__global__ __launch_bounds__(512) void k_gwm(const _Float16* __restrict__ WF,
                                             const float* __restrict__ X,
                                             const float* __restrict__ bias,
                                             float* __restrict__ Y,
                                             float* __restrict__ bnpart) {
  __shared__ _Float16 XT[64 * 136];          // [n][c], stride 136 (16B-aligned rows)
  __shared__ float statP[4][64], statQ[4][64];
  const int tid = threadIdx.x;
  const int n0 = blockIdx.x * 64, oh = blockIdx.y, b = blockIdx.z;
  const float* Xb = X + (size_t)(b * C) * N + n0;
#pragma unroll
  for (int i = 0; i < 4; i++) {              // 2048 float4: c=idx>>4, q=idx&15
    const int idx = tid + i * 512;
    const int c = idx >> 4, q = idx & 15;
    const float4 v = *(const float4*)&Xb[(size_t)c * N + q * 4];
    XT[(q * 4 + 0) * 136 + c] = (_Float16)v.x;
    XT[(q * 4 + 1) * 136 + c] = (_Float16)v.y;
    XT[(q * 4 + 2) * 136 + c] = (_Float16)v.z;
    XT[(q * 4 + 3) * 136 + c] = (_Float16)v.w;
  }
  __syncthreads();
  const int w = tid >> 6, lane = tid & 63, quad = lane >> 4, lr = lane & 15;
  const int nt = w & 3, og = w >> 2;
  const int ob[2] = {oh * 64 + og * 16, oh * 64 + (og + 2) * 16};
  f16x8 aW[2][4];
#pragma unroll
  for (int t = 0; t < 2; t++)
#pragma unroll
    for (int kc = 0; kc < 4; kc++)
      aW[t][kc] = *(const f16x8*)&WF[(size_t)(ob[t] + lr) * 128 + kc * 32 + quad * 8];
  f32x4 acc[2];
  acc[0] = (f32x4){0.f, 0.f, 0.f, 0.f};
  acc[1] = (f32x4){0.f, 0.f, 0.f, 0.f};
#pragma unroll
  for (int kc = 0; kc < 4; kc++) {
    const f16x8 bf = *(const f16x8*)&XT[(nt * 16 + lr) * 136 + kc * 32 + quad * 8];
    acc[0] = __builtin_amdgcn_mfma_f32_16x16x32_f16(aW[0][kc], bf, acc[0], 0, 0, 0);
    acc[1] = __builtin_amdgcn_mfma_f32_16x16x32_f16(aW[1][kc], bf, acc[1], 0, 0, 0);
  }
#pragma unroll
  for (int t = 0; t < 2; t++) {
#pragma unroll
    for (int r = 0; r < 4; r++) {
      const int o = ob[t] + quad * 4 + r;
      const float val = acc[t][r] + (BIAS ? bias[o] : 0.f);
      Y[(size_t)(b * C + o) * N + n0 + nt * 16 + lr] = val;
      if (STAT) {
        float s = val, q = val * val;
        s += __shfl_xor(s, 1, 64); q += __shfl_xor(q, 1, 64);
        s += __shfl_xor(s, 2, 64); q += __shfl_xor(q, 2, 64);
        s += __shfl_xor(s, 4, 64); q += __shfl_xor(q, 4, 64);
        s += __shfl_xor(s, 8, 64); q += __shfl_xor(q, 8, 64);
        if (lr == 0) { statP[nt][o - oh * 64] = s; statQ[nt][o - oh * 64] = q; }
      }
    }
  }
  if (STAT) {
    __syncthreads();
    if (tid < 64) {
      const int o = oh * 64 + tid;
      const float s = statP[0][tid] + statP[1][tid] + statP[2][tid] + statP[3][tid];
      const float q = statQ[0][tid] + statQ[1][tid] + statQ[2][tid] + statQ[3][tid];
      const int part = blockIdx.x * 4 + b;
      bnpart[o * 512 + part] = s;
      bnpart[o * 512 + 256 + part] = q;
    }
  }
}

// ---------------------------------------------------------------------------
// R8: fused XV + QT projection via MFMA (replaces k_gw-XV + k_qkt).
// 160 output rows: o<128 -> XV f16 [b][o][n] (+bias); o>=128 -> QT[b][n][o-128].
// grid (N/32, B), block 256 (4 waves: n-tile w&1, o-tiles {og,og+2,..,og+8}).
// ---------------------------------------------------------------------------
__global__ __launch_bounds__(256) void k_qv(const _Float16* __restrict__ WFv,
                                            const _Float16* __restrict__ WFqk,
                                            const float* __restrict__ X,
                                            const float* __restrict__ bv,
                                            _Float16* __restrict__ XV,
                                            _Float16* __restrict__ QT) {
  __shared__ _Float16 XT[32 * 136];
  const int tid = threadIdx.x;
  const int n0 = blockIdx.x * 32, b = blockIdx.y;
  const float* Xb = X + (size_t)(b * C) * N + n0;
#pragma unroll
  for (int i = 0; i < 4; i++) {              // 1024 float4: c=idx>>3, q=idx&7
    const int idx = tid + i * 256;
    const int c = idx >> 3, q = idx & 7;
    const float4 v = *(const float4*)&Xb[(size_t)c * N + q * 4];
    XT[(q * 4 + 0) * 136 + c] = (_Float16)v.x;
    XT[(q * 4 + 1) * 136 + c] = (_Float16)v.y;
    XT[(q * 4 + 2) * 136 + c] = (_Float16)v.z;
    XT[(q * 4 + 3) * 136 + c] = (_Float16)v.w;
  }
  __syncthreads();
  const int w = tid >> 6, lane = tid & 63, quad = lane >> 4, lr = lane & 15;
  const int nt = w & 1, og = w >> 1;
  f32x4 acc[5];
  const _Float16* Aptr[5];
  int otl[5];
#pragma unroll
  for (int j = 0; j < 5; j++) {
    acc[j] = (f32x4){0.f, 0.f, 0.f, 0.f};
    const int ot = og + 2 * j;
    otl[j] = ot;
    Aptr[j] = (ot < 8) ? (WFv + (size_t)(ot * 16 + lr) * 128)
                       : (WFqk + (size_t)((ot - 8) * 16 + lr) * 128);
  }
#pragma unroll
  for (int kc = 0; kc < 4; kc++) {
    const f16x8 bf = *(const f16x8*)&XT[(nt * 16 + lr) * 136 + kc * 32 + quad * 8];
#pragma unroll
    for (int j = 0; j < 5; j++) {
      const f16x8 a = *(const f16x8*)&Aptr[j][kc * 32 + quad * 8];
      acc[j] = __builtin_amdgcn_mfma_f32_16x16x32_f16(a, bf, acc[j], 0, 0, 0);
    }
  }
#pragma unroll
  for (int j = 0; j < 5; j++) {
    const int ot = otl[j];
    if (ot < 8) {
#pragma unroll
      for (int r = 0; r < 4; r++) {
        const int o = ot * 16 + quad * 4 + r;
        const float val = acc[j][r] + bv[o];
        XV[(size_t)(b * C + o) * N + n0 + nt * 16 + lr] = (_Float16)val;
      }
    } else {
#pragma unroll
      for (int r = 0; r < 4; r++) {
        const int qo = (ot - 8) * 16 + quad * 4 + r;
        QT[((size_t)b * N + n0 + nt * 16 + lr) * 32 + qo] = (_Float16)acc[j][r];
      }
    }
  }
}

// ---------------------------------------------------------------------------
// Flash-style row-stats WITHOUT materializing E (two-pass Gram sweep).
// grid (N/64, B), block 512.
// ---------------------------------------------------------------------------
__global__ __launch_bounds__(512) void k_sm(const _Float16* __restrict__ QT,
                                            const int* __restrict__ mask,
                                            float* __restrict__ rowmax,
                                            float* __restrict__ rowsi) {
  __shared__ float mb[N];          // 0 (valid m) or -1e30 (invalid m)
  __shared__ float red[2][64];
  __shared__ float rmS[64];
  const int tid = threadIdx.x;
  const int n0 = blockIdx.x * 64, b = blockIdx.y;
  const _Float16* Qb = QT + (size_t)b * N * 32;
  const int* Mb = mask + b * N;
#pragma unroll
  for (int i = 0; i < 8; i++) {
    const int v = tid + i * 512;
    mb[v] = (Mb[v] != 0) ? 0.0f : -1e30f;
  }
  const int w = tid >> 6, lane = tid & 63, quad = lane >> 4, lr = lane & 15;
  const int nw = (w & 3) * 16, mh = (w >> 2) * 64;
  const f16x8 aF = *(const f16x8*)&Qb[(size_t)(n0 + nw + lr) * 32 + quad * 8];
  __syncthreads();
  float mx[4] = {-3e38f, -3e38f, -3e38f, -3e38f};
  for (int ms = 0; ms < N; ms += 128) {
#pragma unroll
    for (int t = 0; t < 4; t++) {
      const int mrow = ms + mh + t * 16 + lr;
      const f16x8 bF = *(const f16x8*)&Qb[(size_t)mrow * 32 + quad * 8];
      f32x4 d = (f32x4){0.f, 0.f, 0.f, 0.f};
      d = __builtin_amdgcn_mfma_f32_16x16x32_f16(aF, bF, d, 0, 0, 0);
      const float bias = mb[mrow];
#pragma unroll
      for (int r = 0; r < 4; r++) mx[r] = fmaxf(mx[r], d[r] + bias);
    }
  }
#pragma unroll
  for (int r = 0; r < 4; r++) {
    float v = mx[r];
    v = fmaxf(v, __shfl_xor(v, 1, 64));
    v = fmaxf(v, __shfl_xor(v, 2, 64));
    v = fmaxf(v, __shfl_xor(v, 4, 64));
    v = fmaxf(v, __shfl_xor(v, 8, 64));
    mx[r] = v;
  }
  if (lr == 0)
#pragma unroll
    for (int r = 0; r < 4; r++) red[w >> 2][nw + quad * 4 + r] = mx[r];
  __syncthreads();
  if (tid < 64) rmS[tid] = fmaxf(red[0][tid], red[1][tid]);
  __syncthreads();
  float rmr[4];
#pragma unroll
  for (int r = 0; r < 4; r++) rmr[r] = rmS[nw + quad * 4 + r];
  float s[4] = {0.f, 0.f, 0.f, 0.f};
  for (int ms = 0; ms < N; ms += 128) {
#pragma unroll
    for (int t = 0; t < 4; t++) {
      const int mrow = ms + mh + t * 16 + lr;
      const f16x8 bF = *(const f16x8*)&Qb[(size_t)mrow * 32 + quad * 8];
      f32x4 d = (f32x4){0.f, 0.f, 0.f, 0.f};
      d = __builtin_amdgcn_mfma_f32_16x16x32_f16(aF, bF, d, 0, 0, 0);
      const float bias = mb[mrow];
#pragma unroll
      for (int r = 0; r < 4; r++) s[r] += __expf(d[r] + bias - rmr[r]);
    }
  }
#pragma unroll
  for (int r = 0; r < 4; r++) {
    float v = s[r];
    v += __shfl_xor(v, 1, 64);
    v += __shfl_xor(v, 2, 64);
    v += __shfl_xor(v, 4, 64);
    v += __shfl_xor(v, 8, 64);
    s[r] = v;
  }
  __syncthreads();
  if (lr == 0)
#pragma unroll
    for (int r = 0; r < 4; r++) red[w >> 2][nw + quad * 4 + r] = s[r];
  __syncthreads();
  if (tid < 64) {
    const int row = n0 + tid;
    const float tot = red[0][tid] + red[1][tid];
    const bool valid = (Mb[row] != 0);
    rowmax[b * N + row] = valid ? rmS[tid] : 1e30f;
    rowsi[b * N + row] = valid ? (1.0f / tot) : 0.0f;
  }
}

// ---------------------------------------------------------------------------
// Fused Gram->exp->PV. R8: no XV LDS staging — PV A-fragments load directly
// from global (L2-hot, prefetched one step ahead); LDS holds only Ps (dbuf).
// grid (N/32, B), block 512.
// ---------------------------------------------------------------------------
__global__ __launch_bounds__(512, 4) void k_pv(const _Float16* __restrict__ QT,
                                               const _Float16* __restrict__ XV,
                                               const float* __restrict__ H,
                                               const int* __restrict__ mask,
                                               const float* __restrict__ rowmax,
                                               const float* __restrict__ rowsi,
                                               float* __restrict__ Td) {
  __shared__ _Float16 Ps[2][32 * 72];
  __shared__ float colPart[4][32];
  __shared__ float colS[32];
  const int tid = threadIdx.x;
  const int m0 = blockIdx.x * 32, b = blockIdx.y;
  const _Float16* Qb = QT + (size_t)b * N * 32;
  const _Float16* XVb = XV + (size_t)(b * C) * N;
  const float* rmB = rowmax + b * N;
  const float* riB = rowsi + b * N;
  const int w = tid >> 6, lane = tid & 63, quad = lane >> 4, lr = lane & 15;
  const int msub = w & 1, nsub = w >> 1;
  const int c0 = w * 16;
  const f16x8 aG = *(const f16x8*)&Qb[(size_t)(m0 + msub * 16 + lr) * 32 + quad * 8];
  float vmb[4];
#pragma unroll
  for (int r = 0; r < 4; r++)
    vmb[r] = (mask[b * N + m0 + msub * 16 + quad * 4 + r] != 0) ? 0.0f : -1e30f;
  f32x4 acc[2];
  acc[0] = (f32x4){0.f, 0.f, 0.f, 0.f};
  acc[1] = (f32x4){0.f, 0.f, 0.f, 0.f};
  float cs[4] = {0.f, 0.f, 0.f, 0.f};

  auto loadA0 = [&](int k0) { return *(const f16x8*)&XVb[(size_t)(c0 + lr) * N + k0 + quad * 8]; };
  auto loadA1 = [&](int k0) { return *(const f16x8*)&XVb[(size_t)(c0 + lr) * N + k0 + 32 + quad * 8]; };
  auto produce = [&](int k0, int bf) {
    const int nn = k0 + nsub * 16 + lr;
    const f16x8 bG = *(const f16x8*)&Qb[(size_t)nn * 32 + quad * 8];
    const float rmv = rmB[nn], riv = riB[nn];
    f32x4 e = (f32x4){0.f, 0.f, 0.f, 0.f};
    e = __builtin_amdgcn_mfma_f32_16x16x32_f16(aG, bG, e, 0, 0, 0);
#pragma unroll
    for (int r = 0; r < 4; r++) {
      float p = __expf(e[r] - rmv + vmb[r]) * riv;
      p = (riv == 0.0f) ? 0.000244140625f : p;      // fully-masked row n
      cs[r] += p;
      Ps[bf][(msub * 16 + quad * 4 + r) * 72 + nsub * 16 + lr] = (_Float16)p;
    }
  };

  f16x8 a0c = loadA0(0), a1c = loadA1(0);
  produce(0, 0);
  __syncthreads();
  for (int it = 0; it < 64; it++) {
    const int bf = it & 1, nf = bf ^ 1;
    f16x8 a0n = a0c, a1n = a1c;
    if (it + 1 < 64) {
      a0n = loadA0((it + 1) * 64);
      a1n = loadA1((it + 1) * 64);
      produce((it + 1) * 64, nf);
    }
    {
      const f16x8 b00 = *(const f16x8*)&Ps[bf][lr * 72 + quad * 8];
      const f16x8 b01 = *(const f16x8*)&Ps[bf][lr * 72 + 32 + quad * 8];
      const f16x8 b10 = *(const f16x8*)&Ps[bf][(16 + lr) * 72 + quad * 8];
      const f16x8 b11 = *(const f16x8*)&Ps[bf][(16 + lr) * 72 + 32 + quad * 8];
      acc[0] = __builtin_amdgcn_mfma_f32_16x16x32_f16(a0c, b00, acc[0], 0, 0, 0);
      acc[0] = __builtin_amdgcn_mfma_f32_16x16x32_f16(a1c, b01, acc[0], 0, 0, 0);
      acc[1] = __builtin_amdgcn_mfma_f32_16x16x32_f16(a0c, b10, acc[1], 0, 0, 0);
      acc[1] = __builtin_amdgcn_mfma_f32_16x16x32_f16(a1c, b11, acc[1], 0, 0, 0);
    }
    a0c = a0n; a1c = a1n;
    __syncthreads();
  }
#pragma unroll
  for (int r = 0; r < 4; r++) {
    float v = cs[r];
    v += __shfl_xor(v, 1, 64);
    v += __shfl_xor(v, 2, 64);
    v += __shfl_xor(v, 4, 64);
    v += __shfl_xor(v, 8, 64);
    cs[r] = v;
  }
  if (lr == 0)
#pragma unroll
    for (int r = 0; r < 4; r++) colPart[nsub][msub * 16 + quad * 4 + r] = cs[r];
  __syncthreads();
  if (tid < 32)
    colS[tid] = colPart[0][tid] + colPart[1][tid] + colPart[2][tid] + colPart[3][tid];
  __syncthreads();
  const float rdiv0 = 1.0f / (1e-9f + colS[lr]);
  const float rdiv1 = 1.0f / (1e-9f + colS[16 + lr]);
  const int cg = b * C + w * 16 + quad * 4;
#pragma unroll
  for (int r = 0; r < 4; r++) {
    const size_t gi0 = (size_t)(cg + r) * N + m0 + lr;
    Td[gi0] = H[gi0] - acc[0][r] * rdiv0;
    const size_t gi1 = (size_t)(cg + r) * N + m0 + 16 + lr;
    Td[gi1] = H[gi1] - acc[1][r] * rdiv1;
  }
}

// ---------------------------------------------------------------------------
// Apply BN+ReLU (+residual, +write output slice). grid 2048, 256 thr, float4.
// Each block covers one channel; reduces its 256 BN partial pairs in-block.
// ---------------------------------------------------------------------------
template<bool RES>
__global__ __launch_bounds__(256) void k_apply(const float* __restrict__ T2,
                                               const float* __restrict__ bnpart,
                                               const float* __restrict__ gamma,
                                               const float* __restrict__ beta,
                                               float* __restrict__ H,
                                               float* __restrict__ Out) {
  __shared__ float rs[4], rq[4], bc[2];
  const int tid = threadIdx.x;
  const int f = (blockIdx.x * 256 + tid) * 4;
  const int c = (blockIdx.x >> 2) & 127;
  float s = bnpart[c * 512 + tid];
  float q = bnpart[c * 512 + 256 + tid];
#pragma unroll
  for (int o = 1; o <= 32; o <<= 1) { s += __shfl_xor(s, o, 64); q += __shfl_xor(q, o, 64); }
  if ((tid & 63) == 0) { rs[tid >> 6] = s; rq[tid >> 6] = q; }
  __syncthreads();
  if (tid == 0) {
    const float st = rs[0] + rs[1] + rs[2] + rs[3];
    const float qt = rq[0] + rq[1] + rq[2] + rq[3];
    const float inv = 1.0f / (B * N);
    const float mean = st * inv;
    const float var = qt * inv - mean * mean;   // biased, like torch BN
    const float sc = gamma[c] * rsqrtf(var + 1e-5f);
    bc[0] = sc;
    bc[1] = beta[c] - mean * sc;
  }
  __syncthreads();
  const float sc = bc[0], sh = bc[1];
  const float4 t = *(const float4*)&T2[f];
  float4 r;
  r.x = fmaxf(t.x * sc + sh, 0.f);
  r.y = fmaxf(t.y * sc + sh, 0.f);
  r.z = fmaxf(t.z * sc + sh, 0.f);
  r.w = fmaxf(t.w * sc + sh, 0.f);
  if (RES) {
    const float4 h = *(const float4*)&H[f];
    r.x += h.x; r.y += h.y; r.z += h.z; r.w += h.w;
    *(float4*)&H[f] = r;
    const int b = f >> 19;                // f / (C*N)
    const int rem = f & (C * N - 1);      // c*N + n
    *(float4*)&Out[(size_t)b * (4 * C * N) + rem] = r;
  } else {
    *(float4*)&H[f] = r;
  }
}

// ---------------------------------------------------------------------------
extern "C" void kernel_launch(void* const* d_in, const int* in_sizes, int n_in,
                              void* d_out, int out_size, void* d_ws, size_t ws_size,
                              hipStream_t stream) {
  const float* x    = (const float*)d_in[0];
  const int*   mask = (const int*)  d_in[1];
  const float* w1   = (const float*)d_in[2];
  const float* g1   = (const float*)d_in[3];
  const float* b1   = (const float*)d_in[4];
  const float* w2   = (const float*)d_in[5];
  const float* g2   = (const float*)d_in[6];
  const float* b2   = (const float*)d_in[7];
  const float* wqk  = (const float*)d_in[8];
  const float* wv   = (const float*)d_in[9];
  const float* bv   = (const float*)d_in[10];
  const float* wt   = (const float*)d_in[11];
  const float* bt   = (const float*)d_in[12];
  const float* sg   = (const float*)d_in[13];
  const float* sb   = (const float*)d_in[14];
  float* out = (float*)d_out;

  char* p = (char*)d_ws;
  auto alloc = [&](size_t bytes) { char* r = p; p += (bytes + 255) & ~(size_t)255; return r; };
  float*    H      = (float*)   alloc((size_t)B * C * N * 4);
  float*    T2     = (float*)   alloc((size_t)B * C * N * 4);
  float*    Td     = (float*)   alloc((size_t)B * C * N * 4);
  _Float16* XQKT   = (_Float16*)alloc((size_t)B * N * 32 * 2);
  _Float16* XV     = (_Float16*)alloc((size_t)B * C * N * 2);
  float*    rowmax = (float*)   alloc((size_t)B * N * 4);
  float*    rowsi  = (float*)   alloc((size_t)B * N * 4);
  float*    bnpart = (float*)   alloc((size_t)C * 512 * 4);
  _Float16* WF     = (_Float16*)alloc((size_t)180224 * 2);
  (void)ws_size;
  _Float16* wf1  = WF;
  _Float16* wf2  = WF + 16384;
  _Float16* wfv  = WF + 32768;
  _Float16* wft  = WF + 98304;
  _Float16* wfqk = WF + 163840;

  // ---- one-shot weight convert to f16 ----
  k_wcvt<<<176, 256, 0, stream>>>(w1, w2, wv, wt, wqk, WF);

  // ---- stem: two conv1d(+BN+ReLU), MFMA, BN partials fused ----
  k_gwm<false, true><<<dim3(64, 2, B), 512, 0, stream>>>(wf1, x, nullptr, T2, bnpart);
  k_apply<false><<<2048, 256, 0, stream>>>(T2, bnpart, g1, b1, H, nullptr);
  k_gwm<false, true><<<dim3(64, 2, B), 512, 0, stream>>>(wf2, H, nullptr, T2, bnpart);
  k_apply<false><<<2048, 256, 0, stream>>>(T2, bnpart, g2, b2, H, nullptr);

  // ---- 4 chained offset-attention layers (flash-style, no E buffer) ----
  for (int L = 0; L < 4; L++) {
    k_qv<<<dim3(128, B), 256, 0, stream>>>(wfv + (size_t)L * 16384, wfqk + (size_t)L * 4096,
                                           H, bv + L * C, XV, XQKT);
    k_sm<<<dim3(64, B), 512, 0, stream>>>(XQKT, mask, rowmax, rowsi);
    k_pv<<<dim3(128, B), 512, 0, stream>>>(XQKT, XV, H, mask, rowmax, rowsi, Td);
    k_gwm<true, true><<<dim3(64, 2, B), 512, 0, stream>>>(wft + (size_t)L * 16384, Td, bt + L * C, T2, bnpart);
    k_apply<true><<<2048, 256, 0, stream>>>(T2, bnpart, sg + L * C, sb + L * C, H, out + (size_t)L * C * N);
  }
}

// Round 9
// 582.165 us; speedup vs baseline: 1.1532x; 1.1532x over previous
//
#include <hip/hip_runtime.h>
#include <hip/hip_fp16.h>

constexpr int C = 128;
constexpr int N = 4096;
constexpr int B = 4;

typedef _Float16 f16x8 __attribute__((ext_vector_type(8)));
typedef _Float16 f16x4 __attribute__((ext_vector_type(4)));
typedef float    f32x4 __attribute__((ext_vector_type(4)));

// ---------------------------------------------------------------------------
// One-shot weight convert fp32 -> f16 into workspace, concatenated:
// [w1(16K) | w2(16K) | wv(64K) | wt(64K) | wqk(16K)] elements.
// grid 176, 256 thr; each thread converts one float4.
// ---------------------------------------------------------------------------
__global__ __launch_bounds__(256) void k_wcvt(const float* __restrict__ w1,
                                              const float* __restrict__ w2,
                                              const float* __restrict__ wv,
                                              const float* __restrict__ wt,
                                              const float* __restrict__ wqk,
                                              _Float16* __restrict__ WF) {
  const int g = blockIdx.x * 256 + threadIdx.x;   // float4 index
  const float* src; int off;
  if (g < 4096)       { src = w1;  off = g; }
  else if (g < 8192)  { src = w2;  off = g - 4096; }
  else if (g < 24576) { src = wv;  off = g - 8192; }
  else if (g < 40960) { src = wt;  off = g - 24576; }
  else                { src = wqk; off = g - 40960; }
  const float4 v = ((const float4*)src)[off];
  f16x4 h = {(_Float16)v.x, (_Float16)v.y, (_Float16)v.z, (_Float16)v.w};
  *(f16x4*)&WF[(size_t)g * 4] = h;
}

// ---------------------------------------------------------------------------
// MFMA projection GEMM. Y[b,o,n] = sum_c W[o,c]*X[b,c,n] (+bias), fp32 out.
// W is pre-converted f16 [o][c] (k-contiguous A operand, direct global loads).
// X staged as f16 transposed XT[n][c] in LDS (B^T operand).
// grid (N/64, 2, B), block 512 (8 waves: n-tile w&3, o-tiles {w>>2, w>>2+2}).
// STAT: contention-free BN partials bnpart[o*512 + part(+256)], part=bx*4+b.
// ---------------------------------------------------------------------------
template<bool BIAS, bool STAT>
__global__ __launch_bounds__(512) void k_gwm(const _Float16* __restrict__ WF,
                                             const float* __restrict__ X,
                                             const float* __restrict__ bias,
                                             float* __restrict__ Y,
                                             float* __restrict__ bnpart) {
  __shared__ _Float16 XT[64 * 136];          // [n][c], stride 136 (16B-aligned rows)
  __shared__ float statP[4][64], statQ[4][64];
  const int tid = threadIdx.x;
  const int n0 = blockIdx.x * 64, oh = blockIdx.y, b = blockIdx.z;
  const float* Xb = X + (size_t)(b * C) * N + n0;
#pragma unroll
  for (int i = 0; i < 4; i++) {              // 2048 float4: c=idx>>4, q=idx&15
    const int idx = tid + i * 512;
    const int c = idx >> 4, q = idx & 15;
    const float4 v = *(const float4*)&Xb[(size_t)c * N + q * 4];
    XT[(q * 4 + 0) * 136 + c] = (_Float16)v.x;
    XT[(q * 4 + 1) * 136 + c] = (_Float16)v.y;
    XT[(q * 4 + 2) * 136 + c] = (_Float16)v.z;
    XT[(q * 4 + 3) * 136 + c] = (_Float16)v.w;
  }
  __syncthreads();
  const int w = tid >> 6, lane = tid & 63, quad = lane >> 4, lr = lane & 15;
  const int nt = w & 3, og = w >> 2;
  const int ob[2] = {oh * 64 + og * 16, oh * 64 + (og + 2) * 16};
  f16x8 aW[2][4];
#pragma unroll
  for (int t = 0; t < 2; t++)
#pragma unroll
    for (int kc = 0; kc < 4; kc++)
      aW[t][kc] = *(const f16x8*)&WF[(size_t)(ob[t] + lr) * 128 + kc * 32 + quad * 8];
  f32x4 acc[2];
  acc[0] = (f32x4){0.f, 0.f, 0.f, 0.f};
  acc[1] = (f32x4){0.f, 0.f, 0.f, 0.f};
#pragma unroll
  for (int kc = 0; kc < 4; kc++) {
    const f16x8 bf = *(const f16x8*)&XT[(nt * 16 + lr) * 136 + kc * 32 + quad * 8];
    acc[0] = __builtin_amdgcn_mfma_f32_16x16x32_f16(aW[0][kc], bf, acc[0], 0, 0, 0);
    acc[1] = __builtin_amdgcn_mfma_f32_16x16x32_f16(aW[1][kc], bf, acc[1], 0, 0, 0);
  }
#pragma unroll
  for (int t = 0; t < 2; t++) {
#pragma unroll
    for (int r = 0; r < 4; r++) {
      const int o = ob[t] + quad * 4 + r;
      const float val = acc[t][r] + (BIAS ? bias[o] : 0.f);
      Y[(size_t)(b * C + o) * N + n0 + nt * 16 + lr] = val;
      if (STAT) {
        float s = val, q = val * val;
        s += __shfl_xor(s, 1, 64); q += __shfl_xor(q, 1, 64);
        s += __shfl_xor(s, 2, 64); q += __shfl_xor(q, 2, 64);
        s += __shfl_xor(s, 4, 64); q += __shfl_xor(q, 4, 64);
        s += __shfl_xor(s, 8, 64); q += __shfl_xor(q, 8, 64);
        if (lr == 0) { statP[nt][o - oh * 64] = s; statQ[nt][o - oh * 64] = q; }
      }
    }
  }
  if (STAT) {
    __syncthreads();
    if (tid < 64) {
      const int o = oh * 64 + tid;
      const float s = statP[0][tid] + statP[1][tid] + statP[2][tid] + statP[3][tid];
      const float q = statQ[0][tid] + statQ[1][tid] + statQ[2][tid] + statQ[3][tid];
      const int part = blockIdx.x * 4 + b;
      bnpart[o * 512 + part] = s;
      bnpart[o * 512 + 256 + part] = q;
    }
  }
}

// ---------------------------------------------------------------------------
// Fused XV + QT projection via MFMA (replaces separate XV conv + QK proj).
// 160 output rows: o<128 -> XV f16 [b][o][n] (+bias); o>=128 -> QT[b][n][o-128].
// grid (N/32, B), block 256 (4 waves: n-tile w&1, o-tiles {og,og+2,..,og+8}).
// ---------------------------------------------------------------------------
__global__ __launch_bounds__(256) void k_qv(const _Float16* __restrict__ WFv,
                                            const _Float16* __restrict__ WFqk,
                                            const float* __restrict__ X,
                                            const float* __restrict__ bv,
                                            _Float16* __restrict__ XV,
                                            _Float16* __restrict__ QT) {
  __shared__ _Float16 XT[32 * 136];
  const int tid = threadIdx.x;
  const int n0 = blockIdx.x * 32, b = blockIdx.y;
  const float* Xb = X + (size_t)(b * C) * N + n0;
#pragma unroll
  for (int i = 0; i < 4; i++) {              // 1024 float4: c=idx>>3, q=idx&7
    const int idx = tid + i * 256;
    const int c = idx >> 3, q = idx & 7;
    const float4 v = *(const float4*)&Xb[(size_t)c * N + q * 4];
    XT[(q * 4 + 0) * 136 + c] = (_Float16)v.x;
    XT[(q * 4 + 1) * 136 + c] = (_Float16)v.y;
    XT[(q * 4 + 2) * 136 + c] = (_Float16)v.z;
    XT[(q * 4 + 3) * 136 + c] = (_Float16)v.w;
  }
  __syncthreads();
  const int w = tid >> 6, lane = tid & 63, quad = lane >> 4, lr = lane & 15;
  const int nt = w & 1, og = w >> 1;
  f32x4 acc[5];
  const _Float16* Aptr[5];
  int otl[5];
#pragma unroll
  for (int j = 0; j < 5; j++) {
    acc[j] = (f32x4){0.f, 0.f, 0.f, 0.f};
    const int ot = og + 2 * j;
    otl[j] = ot;
    Aptr[j] = (ot < 8) ? (WFv + (size_t)(ot * 16 + lr) * 128)
                       : (WFqk + (size_t)((ot - 8) * 16 + lr) * 128);
  }
#pragma unroll
  for (int kc = 0; kc < 4; kc++) {
    const f16x8 bf = *(const f16x8*)&XT[(nt * 16 + lr) * 136 + kc * 32 + quad * 8];
#pragma unroll
    for (int j = 0; j < 5; j++) {
      const f16x8 a = *(const f16x8*)&Aptr[j][kc * 32 + quad * 8];
      acc[j] = __builtin_amdgcn_mfma_f32_16x16x32_f16(a, bf, acc[j], 0, 0, 0);
    }
  }
#pragma unroll
  for (int j = 0; j < 5; j++) {
    const int ot = otl[j];
    if (ot < 8) {
#pragma unroll
      for (int r = 0; r < 4; r++) {
        const int o = ot * 16 + quad * 4 + r;
        const float val = acc[j][r] + bv[o];
        XV[(size_t)(b * C + o) * N + n0 + nt * 16 + lr] = (_Float16)val;
      }
    } else {
#pragma unroll
      for (int r = 0; r < 4; r++) {
        const int qo = (ot - 8) * 16 + quad * 4 + r;
        QT[((size_t)b * N + n0 + nt * 16 + lr) * 32 + qo] = (_Float16)acc[j][r];
      }
    }
  }
}

// ---------------------------------------------------------------------------
// Flash-style row-stats WITHOUT materializing E (two-pass Gram sweep).
// grid (N/64, B), block 512.
// ---------------------------------------------------------------------------
__global__ __launch_bounds__(512) void k_sm(const _Float16* __restrict__ QT,
                                            const int* __restrict__ mask,
                                            float* __restrict__ rowmax,
                                            float* __restrict__ rowsi) {
  __shared__ float mb[N];          // 0 (valid m) or -1e30 (invalid m)
  __shared__ float red[2][64];
  __shared__ float rmS[64];
  const int tid = threadIdx.x;
  const int n0 = blockIdx.x * 64, b = blockIdx.y;
  const _Float16* Qb = QT + (size_t)b * N * 32;
  const int* Mb = mask + b * N;
#pragma unroll
  for (int i = 0; i < 8; i++) {
    const int v = tid + i * 512;
    mb[v] = (Mb[v] != 0) ? 0.0f : -1e30f;
  }
  const int w = tid >> 6, lane = tid & 63, quad = lane >> 4, lr = lane & 15;
  const int nw = (w & 3) * 16, mh = (w >> 2) * 64;
  const f16x8 aF = *(const f16x8*)&Qb[(size_t)(n0 + nw + lr) * 32 + quad * 8];
  __syncthreads();
  float mx[4] = {-3e38f, -3e38f, -3e38f, -3e38f};
  for (int ms = 0; ms < N; ms += 128) {
#pragma unroll
    for (int t = 0; t < 4; t++) {
      const int mrow = ms + mh + t * 16 + lr;
      const f16x8 bF = *(const f16x8*)&Qb[(size_t)mrow * 32 + quad * 8];
      f32x4 d = (f32x4){0.f, 0.f, 0.f, 0.f};
      d = __builtin_amdgcn_mfma_f32_16x16x32_f16(aF, bF, d, 0, 0, 0);
      const float bias = mb[mrow];
#pragma unroll
      for (int r = 0; r < 4; r++) mx[r] = fmaxf(mx[r], d[r] + bias);
    }
  }
#pragma unroll
  for (int r = 0; r < 4; r++) {
    float v = mx[r];
    v = fmaxf(v, __shfl_xor(v, 1, 64));
    v = fmaxf(v, __shfl_xor(v, 2, 64));
    v = fmaxf(v, __shfl_xor(v, 4, 64));
    v = fmaxf(v, __shfl_xor(v, 8, 64));
    mx[r] = v;
  }
  if (lr == 0)
#pragma unroll
    for (int r = 0; r < 4; r++) red[w >> 2][nw + quad * 4 + r] = mx[r];
  __syncthreads();
  if (tid < 64) rmS[tid] = fmaxf(red[0][tid], red[1][tid]);
  __syncthreads();
  float rmr[4];
#pragma unroll
  for (int r = 0; r < 4; r++) rmr[r] = rmS[nw + quad * 4 + r];
  float s[4] = {0.f, 0.f, 0.f, 0.f};
  for (int ms = 0; ms < N; ms += 128) {
#pragma unroll
    for (int t = 0; t < 4; t++) {
      const int mrow = ms + mh + t * 16 + lr;
      const f16x8 bF = *(const f16x8*)&Qb[(size_t)mrow * 32 + quad * 8];
      f32x4 d = (f32x4){0.f, 0.f, 0.f, 0.f};
      d = __builtin_amdgcn_mfma_f32_16x16x32_f16(aF, bF, d, 0, 0, 0);
      const float bias = mb[mrow];
#pragma unroll
      for (int r = 0; r < 4; r++) s[r] += __expf(d[r] + bias - rmr[r]);
    }
  }
#pragma unroll
  for (int r = 0; r < 4; r++) {
    float v = s[r];
    v += __shfl_xor(v, 1, 64);
    v += __shfl_xor(v, 2, 64);
    v += __shfl_xor(v, 4, 64);
    v += __shfl_xor(v, 8, 64);
    s[r] = v;
  }
  __syncthreads();
  if (lr == 0)
#pragma unroll
    for (int r = 0; r < 4; r++) red[w >> 2][nw + quad * 4 + r] = s[r];
  __syncthreads();
  if (tid < 64) {
    const int row = n0 + tid;
    const float tot = red[0][tid] + red[1][tid];
    const bool valid = (Mb[row] != 0);
    rowmax[b * N + row] = valid ? rmS[tid] : 1e30f;
    rowsi[b * N + row] = valid ? (1.0f / tot) : 0.0f;
  }
}

// ---------------------------------------------------------------------------
// Fused Gram->exp->PV, R9: reverted to the R7-proven structure (XVs staged in
// LDS with coalesced loads + double-buffered; direct-global A-fragments in R8
// were uncoalesced 16-row-stride loads and regressed 62->87 us).
// One barrier per 64-n step; produce(k+1) overlaps consume(k).
// grid (N/32, B), block 512.
// ---------------------------------------------------------------------------
__global__ __launch_bounds__(512, 4) void k_pv(const _Float16* __restrict__ QT,
                                               const _Float16* __restrict__ XV,
                                               const float* __restrict__ H,
                                               const int* __restrict__ mask,
                                               const float* __restrict__ rowmax,
                                               const float* __restrict__ rowsi,
                                               float* __restrict__ Td) {
  __shared__ _Float16 XVs[2][128 * 72];
  __shared__ _Float16 Ps[2][32 * 72];
  __shared__ float colPart[4][32];
  __shared__ float colS[32];
  const int tid = threadIdx.x;
  const int m0 = blockIdx.x * 32, b = blockIdx.y;
  const _Float16* Qb = QT + (size_t)b * N * 32;
  const _Float16* XVb = XV + (size_t)(b * C) * N;
  const float* rmB = rowmax + b * N;
  const float* riB = rowsi + b * N;
  const int w = tid >> 6, lane = tid & 63, quad = lane >> 4, lr = lane & 15;
  const int msub = w & 1, nsub = w >> 1;
  const f16x8 aG = *(const f16x8*)&Qb[(size_t)(m0 + msub * 16 + lr) * 32 + quad * 8];
  float vmb[4];
#pragma unroll
  for (int r = 0; r < 4; r++)
    vmb[r] = (mask[b * N + m0 + msub * 16 + quad * 4 + r] != 0) ? 0.0f : -1e30f;
  const int sc0 = tid >> 3, sh0 = tid & 7;   // XV staging rows (2 vec/thread)
  const int sc1 = sc0 + 64;
  f32x4 acc[2];
  acc[0] = (f32x4){0.f, 0.f, 0.f, 0.f};
  acc[1] = (f32x4){0.f, 0.f, 0.f, 0.f};
  float cs[4] = {0.f, 0.f, 0.f, 0.f};

  auto produce = [&](int k0, int bf) {
    const int nn = k0 + nsub * 16 + lr;
    const f16x8 bG = *(const f16x8*)&Qb[(size_t)nn * 32 + quad * 8];
    const f16x8 xv0 = *(const f16x8*)&XVb[(size_t)sc0 * N + k0 + sh0 * 8];
    const f16x8 xv1 = *(const f16x8*)&XVb[(size_t)sc1 * N + k0 + sh0 * 8];
    const float rmv = rmB[nn], riv = riB[nn];
    f32x4 e = (f32x4){0.f, 0.f, 0.f, 0.f};
    e = __builtin_amdgcn_mfma_f32_16x16x32_f16(aG, bG, e, 0, 0, 0);
    *(f16x8*)&XVs[bf][sc0 * 72 + sh0 * 8] = xv0;
    *(f16x8*)&XVs[bf][sc1 * 72 + sh0 * 8] = xv1;
#pragma unroll
    for (int r = 0; r < 4; r++) {
      float p = __expf(e[r] - rmv + vmb[r]) * riv;
      p = (riv == 0.0f) ? 0.000244140625f : p;      // fully-masked row n
      cs[r] += p;
      Ps[bf][(msub * 16 + quad * 4 + r) * 72 + nsub * 16 + lr] = (_Float16)p;
    }
  };
  auto consume = [&](int bf) {
    const int c0 = w * 16;
    const f16x8 a0 = *(const f16x8*)&XVs[bf][(c0 + lr) * 72 + quad * 8];
    const f16x8 a1 = *(const f16x8*)&XVs[bf][(c0 + lr) * 72 + 32 + quad * 8];
    const f16x8 b00 = *(const f16x8*)&Ps[bf][lr * 72 + quad * 8];
    const f16x8 b01 = *(const f16x8*)&Ps[bf][lr * 72 + 32 + quad * 8];
    const f16x8 b10 = *(const f16x8*)&Ps[bf][(16 + lr) * 72 + quad * 8];
    const f16x8 b11 = *(const f16x8*)&Ps[bf][(16 + lr) * 72 + 32 + quad * 8];
    acc[0] = __builtin_amdgcn_mfma_f32_16x16x32_f16(a0, b00, acc[0], 0, 0, 0);
    acc[0] = __builtin_amdgcn_mfma_f32_16x16x32_f16(a1, b01, acc[0], 0, 0, 0);
    acc[1] = __builtin_amdgcn_mfma_f32_16x16x32_f16(a0, b10, acc[1], 0, 0, 0);
    acc[1] = __builtin_amdgcn_mfma_f32_16x16x32_f16(a1, b11, acc[1], 0, 0, 0);
  };

  produce(0, 0);
  __syncthreads();
  for (int it = 0; it < 64; it += 2) {
    if (it + 1 < 64) produce((it + 1) * 64, 1);
    consume(0);
    __syncthreads();
    if (it + 2 < 64) produce((it + 2) * 64, 0);
    consume(1);
    __syncthreads();
  }
#pragma unroll
  for (int r = 0; r < 4; r++) {
    float v = cs[r];
    v += __shfl_xor(v, 1, 64);
    v += __shfl_xor(v, 2, 64);
    v += __shfl_xor(v, 4, 64);
    v += __shfl_xor(v, 8, 64);
    cs[r] = v;
  }
  if (lr == 0)
#pragma unroll
    for (int r = 0; r < 4; r++) colPart[nsub][msub * 16 + quad * 4 + r] = cs[r];
  __syncthreads();
  if (tid < 32)
    colS[tid] = colPart[0][tid] + colPart[1][tid] + colPart[2][tid] + colPart[3][tid];
  __syncthreads();
  const float rdiv0 = 1.0f / (1e-9f + colS[lr]);
  const float rdiv1 = 1.0f / (1e-9f + colS[16 + lr]);
  const int cg = b * C + w * 16 + quad * 4;
#pragma unroll
  for (int r = 0; r < 4; r++) {
    const size_t gi0 = (size_t)(cg + r) * N + m0 + lr;
    Td[gi0] = H[gi0] - acc[0][r] * rdiv0;
    const size_t gi1 = (size_t)(cg + r) * N + m0 + 16 + lr;
    Td[gi1] = H[gi1] - acc[1][r] * rdiv1;
  }
}

// ---------------------------------------------------------------------------
// Apply BN+ReLU (+residual, +write output slice). grid 2048, 256 thr, float4.
// Each block covers one channel; reduces its 256 BN partial pairs in-block.
// ---------------------------------------------------------------------------
template<bool RES>
__global__ __launch_bounds__(256) void k_apply(const float* __restrict__ T2,
                                               const float* __restrict__ bnpart,
                                               const float* __restrict__ gamma,
                                               const float* __restrict__ beta,
                                               float* __restrict__ H,
                                               float* __restrict__ Out) {
  __shared__ float rs[4], rq[4], bc[2];
  const int tid = threadIdx.x;
  const int f = (blockIdx.x * 256 + tid) * 4;
  const int c = (blockIdx.x >> 2) & 127;
  float s = bnpart[c * 512 + tid];
  float q = bnpart[c * 512 + 256 + tid];
#pragma unroll
  for (int o = 1; o <= 32; o <<= 1) { s += __shfl_xor(s, o, 64); q += __shfl_xor(q, o, 64); }
  if ((tid & 63) == 0) { rs[tid >> 6] = s; rq[tid >> 6] = q; }
  __syncthreads();
  if (tid == 0) {
    const float st = rs[0] + rs[1] + rs[2] + rs[3];
    const float qt = rq[0] + rq[1] + rq[2] + rq[3];
    const float inv = 1.0f / (B * N);
    const float mean = st * inv;
    const float var = qt * inv - mean * mean;   // biased, like torch BN
    const float sc = gamma[c] * rsqrtf(var + 1e-5f);
    bc[0] = sc;
    bc[1] = beta[c] - mean * sc;
  }
  __syncthreads();
  const float sc = bc[0], sh = bc[1];
  const float4 t = *(const float4*)&T2[f];
  float4 r;
  r.x = fmaxf(t.x * sc + sh, 0.f);
  r.y = fmaxf(t.y * sc + sh, 0.f);
  r.z = fmaxf(t.z * sc + sh, 0.f);
  r.w = fmaxf(t.w * sc + sh, 0.f);
  if (RES) {
    const float4 h = *(const float4*)&H[f];
    r.x += h.x; r.y += h.y; r.z += h.z; r.w += h.w;
    *(float4*)&H[f] = r;
    const int b = f >> 19;                // f / (C*N)
    const int rem = f & (C * N - 1);      // c*N + n
    *(float4*)&Out[(size_t)b * (4 * C * N) + rem] = r;
  } else {
    *(float4*)&H[f] = r;
  }
}

// ---------------------------------------------------------------------------
extern "C" void kernel_launch(void* const* d_in, const int* in_sizes, int n_in,
                              void* d_out, int out_size, void* d_ws, size_t ws_size,
                              hipStream_t stream) {
  const float* x    = (const float*)d_in[0];
  const int*   mask = (const int*)  d_in[1];
  const float* w1   = (const float*)d_in[2];
  const float* g1   = (const float*)d_in[3];
  const float* b1   = (const float*)d_in[4];
  const float* w2   = (const float*)d_in[5];
  const float* g2   = (const float*)d_in[6];
  const float* b2   = (const float*)d_in[7];
  const float* wqk  = (const float*)d_in[8];
  const float* wv   = (const float*)d_in[9];
  const float* bv   = (const float*)d_in[10];
  const float* wt   = (const float*)d_in[11];
  const float* bt   = (const float*)d_in[12];
  const float* sg   = (const float*)d_in[13];
  const float* sb   = (const float*)d_in[14];
  float* out = (float*)d_out;

  char* p = (char*)d_ws;
  auto alloc = [&](size_t bytes) { char* r = p; p += (bytes + 255) & ~(size_t)255; return r; };
  float*    H      = (float*)   alloc((size_t)B * C * N * 4);
  float*    T2     = (float*)   alloc((size_t)B * C * N * 4);
  float*    Td     = (float*)   alloc((size_t)B * C * N * 4);
  _Float16* XQKT   = (_Float16*)alloc((size_t)B * N * 32 * 2);
  _Float16* XV     = (_Float16*)alloc((size_t)B * C * N * 2);
  float*    rowmax = (float*)   alloc((size_t)B * N * 4);
  float*    rowsi  = (float*)   alloc((size_t)B * N * 4);
  float*    bnpart = (float*)   alloc((size_t)C * 512 * 4);
  _Float16* WF     = (_Float16*)alloc((size_t)180224 * 2);
  (void)ws_size;
  _Float16* wf1  = WF;
  _Float16* wf2  = WF + 16384;
  _Float16* wfv  = WF + 32768;
  _Float16* wft  = WF + 98304;
  _Float16* wfqk = WF + 163840;

  // ---- one-shot weight convert to f16 ----
  k_wcvt<<<176, 256, 0, stream>>>(w1, w2, wv, wt, wqk, WF);

  // ---- stem: two conv1d(+BN+ReLU), MFMA, BN partials fused ----
  k_gwm<false, true><<<dim3(64, 2, B), 512, 0, stream>>>(wf1, x, nullptr, T2, bnpart);
  k_apply<false><<<2048, 256, 0, stream>>>(T2, bnpart, g1, b1, H, nullptr);
  k_gwm<false, true><<<dim3(64, 2, B), 512, 0, stream>>>(wf2, H, nullptr, T2, bnpart);
  k_apply<false><<<2048, 256, 0, stream>>>(T2, bnpart, g2, b2, H, nullptr);

  // ---- 4 chained offset-attention layers (flash-style, no E buffer) ----
  for (int L = 0; L < 4; L++) {
    k_qv<<<dim3(128, B), 256, 0, stream>>>(wfv + (size_t)L * 16384, wfqk + (size_t)L * 4096,
                                           H, bv + L * C, XV, XQKT);
    k_sm<<<dim3(64, B), 512, 0, stream>>>(XQKT, mask, rowmax, rowsi);
    k_pv<<<dim3(128, B), 512, 0, stream>>>(XQKT, XV, H, mask, rowmax, rowsi, Td);
    k_gwm<true, true><<<dim3(64, 2, B), 512, 0, stream>>>(wft + (size_t)L * 16384, Td, bt + L * C, T2, bnpart);
    k_apply<true><<<2048, 256, 0, stream>>>(T2, bnpart, sg + L * C, sb + L * C, H, out + (size_t)L * C * N);
  }
}